// Round 7
// baseline (163.921 us; speedup 1.0000x reference)
//
#include <hip/hip_runtime.h>

#define NN 50000            // nodes
#define NE 800000           // edges
#define NF 128              // input features
#define NH 64               // hidden
#define NG 256              // graphs
#define NB 196              // buckets of 256 dst nodes
#define NC 196              // chunks: ceil(NE/CH)
#define CH 4096             // edges per partition block
#define CELL 80             // per-(chunk,bucket) capacity (packed 4B entries)
#define CAP 5120            // per-bucket CSR capacity
#define NGB 782             // gemm blocks: ceil(NN/64)
#define NPB 782             // agg blocks per plane: ceil(NN/64)
#define PS (NN * 32)        // plane stride in ushorts (50000 rows x 32 dims)

typedef __attribute__((ext_vector_type(8))) short bf16x8;
typedef __attribute__((ext_vector_type(4))) float f32x4;

static __device__ __forceinline__ unsigned short f2bf(float f) {
    union { float f; unsigned u; } v; v.f = f;
    unsigned r = v.u + 0x7FFF + ((v.u >> 16) & 1);   // RNE
    return (unsigned short)(r >> 16);
}
static __device__ __forceinline__ float lo16(unsigned u) {
    return __uint_as_float(u << 16);
}
static __device__ __forceinline__ float hi16(unsigned u) {
    return __uint_as_float(u & 0xFFFF0000u);
}
static __device__ __forceinline__ unsigned pack2(float a, float b) {
    return (unsigned)f2bf(a) | ((unsigned)f2bf(b) << 16);
}

// ---------------------------------------------------------------- fused: psum-zero + partition + gemm1(planes) + W2 pack
__global__ __launch_bounds__(256) void prep_gemm(const int* __restrict__ ei,
                                                 int* __restrict__ histg,
                                                 unsigned* __restrict__ ebuf,
                                                 const float* __restrict__ X,
                                                 const float* __restrict__ W,
                                                 const float* __restrict__ W2,
                                                 unsigned short* __restrict__ Y,
                                                 float* __restrict__ psum,
                                                 unsigned* __restrict__ W2p) {
    __shared__ __align__(16) char smem[35840];
    const int t = threadIdx.x;

    if (blockIdx.x < NC) {
        // ---------------- partition path ----------------
        int* hist = (int*)smem;                    // 256
        int* incl = hist + 256;                    // 256
        int* lcur = incl + 256;                    // 256
        int* wq   = lcur + 256;                    // 4
        unsigned* lpairs = (unsigned*)(smem + 4096); // 4096 entries
        const int c = blockIdx.x;
        const int c0 = c * CH;

        hist[t] = 0;
        __syncthreads();

        int es[16], ed[16];
#pragma unroll
        for (int j = 0; j < 4; ++j) {
            const int e = c0 + (j * 256 + t) * 4;
            int4 s4 = make_int4(-1, -1, -1, -1);
            int4 d4 = make_int4(-1, -1, -1, -1);
            if (e + 3 < NE) {
                s4 = *(const int4*)&ei[e];
                d4 = *(const int4*)&ei[NE + e];
            } else {
                if (e < NE)     { s4.x = ei[e];     d4.x = ei[NE + e]; }
                if (e + 1 < NE) { s4.y = ei[e + 1]; d4.y = ei[NE + e + 1]; }
                if (e + 2 < NE) { s4.z = ei[e + 2]; d4.z = ei[NE + e + 2]; }
            }
            es[4*j] = s4.x; es[4*j+1] = s4.y; es[4*j+2] = s4.z; es[4*j+3] = s4.w;
            ed[4*j] = d4.x; ed[4*j+1] = d4.y; ed[4*j+2] = d4.z; ed[4*j+3] = d4.w;
            if (d4.x >= 0) atomicAdd(&hist[d4.x >> 8], 1);
            if (d4.y >= 0) atomicAdd(&hist[d4.y >> 8], 1);
            if (d4.z >= 0) atomicAdd(&hist[d4.z >> 8], 1);
            if (d4.w >= 0) atomicAdd(&hist[d4.w >> 8], 1);
        }
        __syncthreads();

        // shfl-based inclusive scan of hist[256] (2 barriers)
        const int v = hist[t];
        int sv = v;
#pragma unroll
        for (int off = 1; off < 64; off <<= 1) {
            int u = __shfl_up(sv, off, 64);
            if ((t & 63) >= off) sv += u;
        }
        if ((t & 63) == 63) wq[t >> 6] = sv;
        __syncthreads();
        {
            const int wid = t >> 6;
            int add = 0;
            if (wid > 0) add += wq[0];
            if (wid > 1) add += wq[1];
            if (wid > 2) add += wq[2];
            sv += add;
        }
        incl[t] = sv;
        lcur[t] = sv - v;
        if (t < NB) histg[c * NB + t] = v;
        __syncthreads();

#pragma unroll
        for (int j = 0; j < 16; ++j) {
            const int d = ed[j];
            if (d >= 0) {
                int p = atomicAdd(&lcur[d >> 8], 1);
                lpairs[p] = (unsigned)es[j] | ((unsigned)d << 16);
            }
        }
        __syncthreads();

        const int total = incl[255];
        for (int p = t; p < total; p += 256) {
            const unsigned pr = lpairs[p];
            const int b = pr >> 24;                       // dst>>8
            const int i = p - (incl[b] - hist[b]);
            ebuf[(b * NC + c) * CELL + i] = pr;
        }
    } else {
        const int gb = blockIdx.x - NC;
        if (gb >= NGB) {
            // ---------------- W2 pack path (single block) ----------------
            for (int idx = t; idx < 2048; idx += 256) {
                const int n = idx >> 5, kp = idx & 31;
                W2p[idx] = pack2(W2[(2 * kp) * 64 + n], W2[(2 * kp + 1) * 64 + n]);
            }
            return;
        }
        // ---------------- gemm1 path (writes PLANE layout) ----------------
        if (gb < 17) {   // zero psum (16384) + cnt (256)
            const int o = gb * 1024 + t * 4;
            if (o < 16640) *(float4*)&psum[o] = make_float4(0.f, 0.f, 0.f, 0.f);
        }

        unsigned short* Xs = (unsigned short*)smem;       // 64*136 bf16
        unsigned int* Wt = (unsigned int*)(smem + 17408); // 64*68 packed
        const int base = gb * 64;

        for (int i = t * 4; i < 64 * 128; i += 1024) {
            int node = i >> 7, k = i & 127;
            int gn = base + node; if (gn >= NN) gn = NN - 1;
            float4 v = *(const float4*)&X[(size_t)gn * 128 + k];
            ushort4 o = { f2bf(v.x), f2bf(v.y), f2bf(v.z), f2bf(v.w) };
            *(ushort4*)&Xs[node * 136 + k] = o;
        }
        for (int idx = t; idx < 64 * 64; idx += 256) {
            int n = idx & 63, kp = idx >> 6;
            float w0 = W[(2 * kp) * 64 + n];
            float w1 = W[(2 * kp + 1) * 64 + n];
            Wt[n * 68 + kp] = (unsigned)f2bf(w0) | ((unsigned)f2bf(w1) << 16);
        }
        __syncthreads();

        const int w = t >> 6;
        const int lane = t & 63;
        const int l15 = lane & 15;
        const int quad = lane >> 4;
        f32x4 acc[4] = {{0.f,0.f,0.f,0.f},{0.f,0.f,0.f,0.f},{0.f,0.f,0.f,0.f},{0.f,0.f,0.f,0.f}};
#pragma unroll
        for (int kk = 0; kk < 4; ++kk) {
            const bf16x8 a = *(const bf16x8*)&Xs[(w * 16 + l15) * 136 + quad * 8 + kk * 32];
#pragma unroll
            for (int nt = 0; nt < 4; ++nt) {
                const bf16x8 b = *(const bf16x8*)&Wt[(nt * 16 + l15) * 68 + quad * 4 + kk * 16];
                acc[nt] = __builtin_amdgcn_mfma_f32_16x16x32_bf16(a, b, acc[nt], 0, 0, 0);
            }
        }
        const int r0 = base + w * 16 + quad * 4;
#pragma unroll
        for (int reg = 0; reg < 4; ++reg) {
            const int row = r0 + reg;
            if (row < NN) {
#pragma unroll
                for (int nt = 0; nt < 4; ++nt) {
                    const int p = nt >> 1;
                    Y[(size_t)p * PS + row * 32 + (nt & 1) * 16 + l15] = f2bf(acc[nt][reg]);
                }
            }
        }
    }
}

// ---------------------------------------------------------------- level-2: per-bucket CSR + dis (R4's proven 512-thread version)
__global__ __launch_bounds__(512) void build_csr(const unsigned* __restrict__ ebuf,
                                                 const int* __restrict__ histg,
                                                 int2* __restrict__ row_range,
                                                 float* __restrict__ dis,
                                                 int* __restrict__ csr_src) {
    const int b = blockIdx.x, t = threadIdx.x;
    const int e0 = b * CAP;
    __shared__ int coffs[256];
    __shared__ int cvs[256];
    __shared__ int deg_l[256];
    __shared__ int pre[256];
    __shared__ int cur[256];
    __shared__ int wq[8];
    __shared__ unsigned lpairs[CAP];
    __shared__ int lsrc[CAP];

    int cv = 0;
    if (t < NC) cv = histg[t * NB + b];
    int sv = cv;
    if (t < 256) {
#pragma unroll
        for (int off = 1; off < 64; off <<= 1) {
            int u = __shfl_up(sv, off, 64);
            if ((t & 63) >= off) sv += u;
        }
        if ((t & 63) == 63) wq[t >> 6] = sv;
        deg_l[t] = (b * 256 + t < NN) ? 1 : 0;   // self-loop
        cvs[t] = cv;
    }
    __syncthreads();
    if (t < 256) {
        const int wid = t >> 6;
        int add = 0;
        if (wid > 0) add += wq[0];
        if (wid > 1) add += wq[1];
        if (wid > 2) add += wq[2];
        coffs[t] = sv + add;
    }
    __syncthreads();

    // copy cells -> lpairs, 2 threads per cell (even/odd uint4 groups)
    {
        const int tc = t & 255;
        const int cv2 = cvs[tc];
        if (tc < NC && cv2 > 0) {
            const uint4* src4 = (const uint4*)&ebuf[(size_t)(b * NC + tc) * CELL];
            const int dst = coffs[tc] - cv2;
            for (int g4 = (t >> 8); g4 * 4 < cv2; g4 += 2) {
                const uint4 u = src4[g4];
                const int i = g4 * 4;
                lpairs[dst + i] = u.x;
                if (i + 1 < cv2) lpairs[dst + i + 1] = u.y;
                if (i + 2 < cv2) lpairs[dst + i + 2] = u.z;
                if (i + 3 < cv2) lpairs[dst + i + 3] = u.w;
            }
        }
    }
    __syncthreads();

    const int total = coffs[255];
    for (int i = t; i < total; i += 512)
        atomicAdd(&deg_l[(lpairs[i] >> 16) & 255], 1);
    __syncthreads();

    int dvi = 0, psv = 0;
    if (t < 256) {
        dvi = deg_l[t];
        psv = dvi;
#pragma unroll
        for (int off = 1; off < 64; off <<= 1) {
            int u = __shfl_up(psv, off, 64);
            if ((t & 63) >= off) psv += u;
        }
        if ((t & 63) == 63) wq[4 + (t >> 6)] = psv;
    }
    __syncthreads();
    if (t < 256) {
        const int wid = t >> 6;
        int add = 0;
        if (wid > 0) add += wq[4];
        if (wid > 1) add += wq[5];
        if (wid > 2) add += wq[6];
        psv += add;
        pre[t] = psv;
        cur[t] = 1;                        // slot 0 = self-loop
        const int nd = b * 256 + t;
        if (nd < NN) {
            const int excl = psv - dvi;
            lsrc[excl] = nd;
            row_range[nd] = make_int2(e0 + excl, e0 + psv);
            dis[nd] = rsqrtf((float)dvi);  // dvi = deg+1
        }
    }
    __syncthreads();

    for (int i = t; i < total; i += 512) {
        const unsigned p = lpairs[i];
        const int d = (p >> 16) & 255;
        const int pos = (pre[d] - deg_l[d]) + atomicAdd(&cur[d], 1);
        lsrc[pos] = (int)(p & 0xFFFFu);
    }
    __syncthreads();
    const int tot_all = pre[255];
    for (int i = t; i < tot_all; i += 512)
        csr_src[e0 + i] = lsrc[i];
}

// ---------------------------------------------------------------- plane gather cores (row stride 32 ushorts = 64 B)
static __device__ __forceinline__ void acc8(float* acc, const uint4 u) {
    acc[0] += lo16(u.x); acc[1] += hi16(u.x);
    acc[2] += lo16(u.y); acc[3] += hi16(u.y);
    acc[4] += lo16(u.z); acc[5] += hi16(u.z);
    acc[6] += lo16(u.w); acc[7] += hi16(u.w);
}
static __device__ __forceinline__ void fma8(float* acc, const uint4 u, const float d) {
    acc[0] = fmaf(lo16(u.x), d, acc[0]); acc[1] = fmaf(hi16(u.x), d, acc[1]);
    acc[2] = fmaf(lo16(u.y), d, acc[2]); acc[3] = fmaf(hi16(u.y), d, acc[3]);
    acc[4] = fmaf(lo16(u.z), d, acc[4]); acc[5] = fmaf(hi16(u.z), d, acc[5]);
    acc[6] = fmaf(lo16(u.w), d, acc[6]); acc[7] = fmaf(hi16(u.w), d, acc[7]);
}

// pre-scaled plane rows (layer 2)
static __device__ __forceinline__ void gatherP(const unsigned short* __restrict__ h,
                                               const int* __restrict__ csr,
                                               int lo, int hi, int off8, float* acc) {
    int i = lo;
    for (; i + 8 <= hi; i += 8) {
        int idx[8];
#pragma unroll
        for (int j = 0; j < 8; ++j) idx[j] = csr[i + j];
        uint4 u[8];
#pragma unroll
        for (int j = 0; j < 8; ++j) u[j] = *(const uint4*)&h[(idx[j] << 5) + off8];
#pragma unroll
        for (int j = 0; j < 8; ++j) acc8(acc, u[j]);
    }
    if (i + 4 <= hi) {
        int idx[4];
#pragma unroll
        for (int j = 0; j < 4; ++j) idx[j] = csr[i + j];
        uint4 u[4];
#pragma unroll
        for (int j = 0; j < 4; ++j) u[j] = *(const uint4*)&h[(idx[j] << 5) + off8];
#pragma unroll
        for (int j = 0; j < 4; ++j) acc8(acc, u[j]);
        i += 4;
    }
    if (i + 2 <= hi) {
        const int i0 = csr[i], i1 = csr[i + 1];
        const uint4 u0 = *(const uint4*)&h[(i0 << 5) + off8];
        const uint4 u1 = *(const uint4*)&h[(i1 << 5) + off8];
        acc8(acc, u0); acc8(acc, u1);
        i += 2;
    }
    if (i < hi) acc8(acc, *(const uint4*)&h[(csr[i] << 5) + off8]);
}

// unscaled plane rows (layer 1): fold dis[src] at accumulate time
static __device__ __forceinline__ void gatherP_scaled(const unsigned short* __restrict__ h,
                                                      const int* __restrict__ csr,
                                                      const float* __restrict__ dis,
                                                      int lo, int hi, int off8, float* acc) {
    int i = lo;
    for (; i + 8 <= hi; i += 8) {
        int idx[8];
#pragma unroll
        for (int j = 0; j < 8; ++j) idx[j] = csr[i + j];
        float d[8];
#pragma unroll
        for (int j = 0; j < 8; ++j) d[j] = dis[idx[j]];
        uint4 u[8];
#pragma unroll
        for (int j = 0; j < 8; ++j) u[j] = *(const uint4*)&h[(idx[j] << 5) + off8];
#pragma unroll
        for (int j = 0; j < 8; ++j) fma8(acc, u[j], d[j]);
    }
    if (i + 4 <= hi) {
        int idx[4];
#pragma unroll
        for (int j = 0; j < 4; ++j) idx[j] = csr[i + j];
        float d[4];
#pragma unroll
        for (int j = 0; j < 4; ++j) d[j] = dis[idx[j]];
        uint4 u[4];
#pragma unroll
        for (int j = 0; j < 4; ++j) u[j] = *(const uint4*)&h[(idx[j] << 5) + off8];
#pragma unroll
        for (int j = 0; j < 4; ++j) fma8(acc, u[j], d[j]);
        i += 4;
    }
    if (i + 2 <= hi) {
        const int i0 = csr[i], i1 = csr[i + 1];
        const float d0 = dis[i0], d1 = dis[i1];
        const uint4 u0 = *(const uint4*)&h[(i0 << 5) + off8];
        const uint4 u1 = *(const uint4*)&h[(i1 << 5) + off8];
        fma8(acc, u0, d0); fma8(acc, u1, d1);
        i += 2;
    }
    if (i < hi) {
        const int i0 = csr[i];
        fma8(acc, *(const uint4*)&h[(i0 << 5) + off8], dis[i0]);
    }
}

// ---------------------------------------------------------------- agg1: layer-1 aggregation, plane-parallel (64 nodes/block, 4 lanes/node)
// blocks [0,NPB): plane 0; [NPB,2*NPB): plane 1 — each plane's hot set is 3.2 MB (fits 4 MiB per-XCD L2)
__global__ __launch_bounds__(256) void agg1(const unsigned short* __restrict__ h,
                                            const int2* __restrict__ row_range,
                                            const int* __restrict__ csr_src,
                                            const float* __restrict__ dis,
                                            const float* __restrict__ b1,
                                            unsigned short* __restrict__ bufH) {
    const int t = threadIdx.x;
    const int half = (blockIdx.x >= NPB) ? 1 : 0;
    const int gb = blockIdx.x - half * NPB;
    const int nloc = t >> 2;
    const int off8 = (t & 3) * 8;
    const int n = gb * 64 + nloc;
    if (n >= NN) return;                       // no barriers in this kernel
    const unsigned short* hp = h + (size_t)half * PS;
    const int2 rr = row_range[n];
    float acc[8] = {};
    gatherP_scaled(hp, csr_src, dis, rr.x, rr.y, off8, acc);
    const float dn = dis[n];
    const float4 bv0 = *(const float4*)&b1[half * 32 + off8];
    const float4 bv1 = *(const float4*)&b1[half * 32 + off8 + 4];
    acc[0] = fmaxf(acc[0] * dn + bv0.x, 0.f);
    acc[1] = fmaxf(acc[1] * dn + bv0.y, 0.f);
    acc[2] = fmaxf(acc[2] * dn + bv0.z, 0.f);
    acc[3] = fmaxf(acc[3] * dn + bv0.w, 0.f);
    acc[4] = fmaxf(acc[4] * dn + bv1.x, 0.f);
    acc[5] = fmaxf(acc[5] * dn + bv1.y, 0.f);
    acc[6] = fmaxf(acc[6] * dn + bv1.z, 0.f);
    acc[7] = fmaxf(acc[7] * dn + bv1.w, 0.f);
    uint4 pk;
    pk.x = pack2(acc[0], acc[1]);
    pk.y = pack2(acc[2], acc[3]);
    pk.z = pack2(acc[4], acc[5]);
    pk.w = pack2(acc[6], acc[7]);
    *(uint4*)&bufH[(size_t)n * 64 + half * 32 + off8] = pk;
}

// ---------------------------------------------------------------- gemm2: bufH @ W2, dis-scaled, plane output (64 rows/block)
__global__ __launch_bounds__(256) void gemm2(const unsigned short* __restrict__ bufH,
                                             const unsigned* __restrict__ W2p,
                                             const float* __restrict__ dis,
                                             unsigned short* __restrict__ bufB) {
    __shared__ unsigned short Ah[64 * 72];
    __shared__ unsigned short W2b[64 * 72];
    const int t = threadIdx.x;
    const int base = blockIdx.x * 64;
    // stage 64 rows of bufH (bufH has 50176-row slack; garbage rows' outputs are store-guarded)
    for (int i = t * 8; i < 64 * 64; i += 2048) {
        const int node = i >> 6, k = i & 63;
        *(uint4*)&Ah[node * 72 + k] = *(const uint4*)&bufH[(size_t)(base + node) * 64 + k];
    }
    for (int idx = t; idx < 2048; idx += 256) {
        const int nn2 = idx >> 5, kp = idx & 31;
        *(unsigned*)&W2b[nn2 * 72 + 2 * kp] = W2p[idx];
    }
    __syncthreads();

    const int w = t >> 6;
    const int lane = t & 63;
    const int l15 = lane & 15;
    const int quad = lane >> 4;
    f32x4 acc[4] = {{0.f,0.f,0.f,0.f},{0.f,0.f,0.f,0.f},{0.f,0.f,0.f,0.f},{0.f,0.f,0.f,0.f}};
#pragma unroll
    for (int kk = 0; kk < 2; ++kk) {
        const bf16x8 a = *(const bf16x8*)&Ah[(w * 16 + l15) * 72 + quad * 8 + kk * 32];
#pragma unroll
        for (int nt = 0; nt < 4; ++nt) {
            const bf16x8 b = *(const bf16x8*)&W2b[(nt * 16 + l15) * 72 + quad * 8 + kk * 32];
            acc[nt] = __builtin_amdgcn_mfma_f32_16x16x32_bf16(a, b, acc[nt], 0, 0, 0);
        }
    }
    const int r0 = base + w * 16 + quad * 4;
    float4 d4 = *(const float4*)&dis[r0];   // tail over-read; stores guarded
    const float dd[4] = { d4.x, d4.y, d4.z, d4.w };
#pragma unroll
    for (int reg = 0; reg < 4; ++reg) {
        const int row = r0 + reg;
        if (row < NN) {
#pragma unroll
            for (int nt = 0; nt < 4; ++nt) {
                const int p = nt >> 1;
                bufB[(size_t)p * PS + row * 32 + (nt & 1) * 16 + l15] = f2bf(acc[nt][reg] * dd[reg]);
            }
        }
    }
}

// ---------------------------------------------------------------- agg2 + pooling, plane-parallel (64 nodes/block)
__global__ __launch_bounds__(256) void agg2_pool(const unsigned short* __restrict__ h,
                                                 const int2* __restrict__ row_range,
                                                 const int* __restrict__ csr_src,
                                                 const float* __restrict__ dis,
                                                 const float* __restrict__ b2,
                                                 const int* __restrict__ batch,
                                                 float* __restrict__ psum,
                                                 float* __restrict__ cnt) {
    __shared__ float rowsL[64 * 36];
    __shared__ int nb[64];
    const int t = threadIdx.x;
    const int half = (blockIdx.x >= NPB) ? 1 : 0;
    const int gb = blockIdx.x - half * NPB;
    const int nloc = t >> 2;
    const int off8 = (t & 3) * 8;
    const int n = gb * 64 + nloc;
    if ((t & 3) == 0) nb[nloc] = (n < NN) ? batch[n] : -1;
    if (n < NN) {
        const unsigned short* hp = h + (size_t)half * PS;
        const int2 rr = row_range[n];
        float acc[8] = {};
        gatherP(hp, csr_src, rr.x, rr.y, off8, acc);
        const float dn = dis[n];
        const float4 bv0 = *(const float4*)&b2[half * 32 + off8];
        const float4 bv1 = *(const float4*)&b2[half * 32 + off8 + 4];
        float4 r0, r1;
        r0.x = fmaxf(acc[0] * dn + bv0.x, 0.f);
        r0.y = fmaxf(acc[1] * dn + bv0.y, 0.f);
        r0.z = fmaxf(acc[2] * dn + bv0.z, 0.f);
        r0.w = fmaxf(acc[3] * dn + bv0.w, 0.f);
        r1.x = fmaxf(acc[4] * dn + bv1.x, 0.f);
        r1.y = fmaxf(acc[5] * dn + bv1.y, 0.f);
        r1.z = fmaxf(acc[6] * dn + bv1.z, 0.f);
        r1.w = fmaxf(acc[7] * dn + bv1.w, 0.f);
        *(float4*)&rowsL[nloc * 36 + off8] = r0;
        *(float4*)&rowsL[nloc * 36 + off8 + 4] = r1;
    }
    __syncthreads();
    if (t < 32) {
        float s = 0.f; int curg = -2; int rl = 0;
        for (int r = 0; r < 64; ++r) {
            const int gg = nb[r];                 // wave-uniform
            if (gg != curg) {
                if (curg >= 0) {
                    atomicAdd(&psum[curg * 64 + half * 32 + t], s);
                    if (t == 0 && half == 0) atomicAdd(&cnt[curg], (float)rl);
                }
                s = 0.f; rl = 0; curg = gg;
            }
            if (gg >= 0) { s += rowsL[r * 36 + t]; ++rl; }
        }
        if (curg >= 0) {
            atomicAdd(&psum[curg * 64 + half * 32 + t], s);
            if (t == 0 && half == 0) atomicAdd(&cnt[curg], (float)rl);
        }
    }
}

// ---------------------------------------------------------------- head: mean + MLP
__global__ __launch_bounds__(64) void head_kernel(const float* __restrict__ psum,
                                                  const float* __restrict__ cnt,
                                                  const float* __restrict__ Wm1,
                                                  const float* __restrict__ bm1,
                                                  const float* __restrict__ Wm2,
                                                  const float* __restrict__ bm2,
                                                  float* __restrict__ out) {
    const int g = blockIdx.x;
    const int t = threadIdx.x;
    __shared__ float pl[64];
    const float inv = 1.f / fmaxf(cnt[g], 1.f);
    pl[t] = psum[g * 64 + t] * inv;
    __syncthreads();
    float z = bm1[t];
#pragma unroll 8
    for (int k = 0; k < 64; ++k)
        z += pl[k] * Wm1[k * 64 + t];
    z = fmaxf(z, 0.f);
    float y = z * Wm2[t];
    for (int off = 32; off; off >>= 1) y += __shfl_down(y, off);
    if (t == 0) out[g] = y + bm2[0];
}

// ---------------------------------------------------------------- launch
extern "C" void kernel_launch(void* const* d_in, const int* in_sizes, int n_in,
                              void* d_out, int out_size, void* d_ws, size_t ws_size,
                              hipStream_t stream) {
    const float* x   = (const float*)d_in[0];
    const int*   ei  = (const int*)d_in[1];
    const int*   bat = (const int*)d_in[2];
    const float* W1  = (const float*)d_in[3];
    const float* b1  = (const float*)d_in[4];
    const float* W2  = (const float*)d_in[5];
    const float* b2  = (const float*)d_in[6];
    const float* Wm1 = (const float*)d_in[7];
    const float* bm1 = (const float*)d_in[8];
    const float* Wm2 = (const float*)d_in[9];
    const float* bm2 = (const float*)d_in[10];
    float* out = (float*)d_out;

    char* w = (char*)d_ws;
    int*            histg     = (int*)           (w + 0);          //   153664 B
    int2*           row_range = (int2*)          (w + 153664);     //   400000 B
    float*          dis       = (float*)         (w + 553664);     //   200000 B
    int*            csr_src   = (int*)           (w + 753664);     //  4014080 B
    unsigned*       ebuf      = (unsigned*)      (w + 4767744);    // 12293120 B (packed 4B edges)
    unsigned short* bufA      = (unsigned short*)(w + 17060864);   //  6400000 B (2 planes of 32 dims)
    unsigned short* bufH      = (unsigned short*)(w + 23460864);   //  6422528 B (50176-row slack)
    unsigned short* bufB      = (unsigned short*)(w + 29883392);   //  6400000 B (2 planes of 32 dims)
    float*          psum      = (float*)         (w + 36283392);   //    66560 B (16384 psum + 256 cnt)
    unsigned*       W2p       = (unsigned*)      (w + 36349952);   //     8192 B
    float*          cnt       = psum + 16384;

    prep_gemm <<<NC + NGB + 1, 256, 0, stream>>>(ei, histg, ebuf, x, W1, W2, bufA, psum, W2p);
    build_csr <<<NB, 512, 0, stream>>>(ebuf, histg, row_range, dis, csr_src);
    agg1      <<<2 * NPB, 256, 0, stream>>>(bufA, row_range, csr_src, dis, b1, bufH);
    gemm2     <<<NGB, 256, 0, stream>>>(bufH, W2p, dis, bufB);
    agg2_pool <<<2 * NPB, 256, 0, stream>>>(bufB, row_range, csr_src, dis, b2, bat, psum, cnt);
    head_kernel<<<NG, 64, 0, stream>>>(psum, cnt, Wm1, bm1, Wm2, bm2, out);
}